// Round 8
// baseline (146.491 us; speedup 1.0000x reference)
//
#include <hip/hip_runtime.h>

// Problem constants (reference: B=256, L=512, N=4)
constexpr int B  = 256;
constexpr int TI = 4;             // i-rows per block (in registers)
constexpr int TJ = 4;             // j's per block
constexpr int NG = 64;            // row groups (256/4)
constexpr int NBLK = NG * (NG + 1) / 2;   // 2080 upper-tri 4x4 tiles (incl diagonal)

#define MARGIN 1e-3f
#define LOG2E  1.4426950408889634f
#define LN2    0.6931471805599453

// ---- workspace layout (bytes); all locations read are written every call ----
constexpr size_t OFF_SLAB = 0;        // float slab[2080][4]   (33280 B)
constexpr size_t OFF_CNT  = 65536;    // float cntp[8][4]      (128 B)
constexpr size_t OFF_PSC  = 69632;    // float psc[256*512*4]  (2 MB) preds*log2e
constexpr size_t OFF_PK   = 2166784;  // uchar pk[256][256]    (64 KB) packed masks

// ---------------------------------------------------------------------------
// Prep: b<512  : psc = preds * log2e (float4 streaming)
//       b<768  : pack masks -> 1 byte per (row, lane): bits 0..3 = l=t (n=0..3),
//                bits 4..7 = l=t+256 (n=0..3)
//       b<776  : cntp[p][n] = exact masked-pair count partials via column
//                popcounts: mask_sum[n] = sum_l C(colcount(l,n), 2)
// ---------------------------------------------------------------------------
__global__ __launch_bounds__(256) void prep_kernel(
    const float* __restrict__ preds,
    const int*   __restrict__ masks,
    float*        __restrict__ psc,
    unsigned char* __restrict__ pk,
    float*        __restrict__ cntp)
{
    const int b = blockIdx.x;
    const int t = threadIdx.x;
    __shared__ float sredc[256];

    if (b < 512) {
        const int idx = b * 256 + t;                  // float4 index
        float4 v = ((const float4*)preds)[idx];
        v.x *= LOG2E; v.y *= LOG2E; v.z *= LOG2E; v.w *= LOG2E;
        ((float4*)psc)[idx] = v;
    } else if (b < 768) {
        const int r = b - 512;                        // mask row
        const int4 m0 = ((const int4*)masks)[r * 512 + t];        // l = t
        const int4 m1 = ((const int4*)masks)[r * 512 + t + 256];  // l = t+256
        const unsigned byte =
            (unsigned)m0.x | ((unsigned)m0.y << 1) | ((unsigned)m0.z << 2) |
            ((unsigned)m0.w << 3) | ((unsigned)m1.x << 4) | ((unsigned)m1.y << 5) |
            ((unsigned)m1.z << 6) | ((unsigned)m1.w << 7);
        pk[r * 256 + t] = (unsigned char)byte;
    } else {
        const int p   = b - 768;                      // 0..7
        const int col = p * 256 + t;                  // (l, n) column
        int c = 0;
        #pragma unroll 8
        for (int r = 0; r < 256; ++r) c += masks[r * 2048 + col];
        sredc[t] = (float)((c * (c - 1)) / 2);        // C(c,2) exact in f32
        __syncthreads();
        if (t < 4) {                                  // n = col & 3 = t
            float s = 0.f;
            for (int q = t; q < 256; q += 4) s += sredc[q];
            cntp[p * 4 + t] = s;                      // non-atomic, fixed slot
        }
    }
}

// ---------------------------------------------------------------------------
// Main: block bid -> upper-tri 4x4 tile (g,h), h>=g: rows i0..i0+3 (= 4g..)
// in registers, cols j = 4h..4h+3. Off-diagonal tiles are fully valid (16
// pairs); diagonal tiles (g==h) mask i>=j pairs. j <= 255 always -> no clamp.
// ELEM identity: bce/ln2 = log2(1 + 2^(tg ? -u : u)),  u = (pi-pj)*log2e.
// amdgpu_waves_per_eu(4,4): pin occupancy target so the compiler allocates
// up to 128 VGPRs and keeps the i-tile register-resident (round-7 lesson:
// the occupancy heuristic shrank to 52 VGPRs and rematerialized the tile).
// ---------------------------------------------------------------------------
__global__ __launch_bounds__(256)
__attribute__((amdgpu_waves_per_eu(4, 4)))
void pair_bce_kernel(
    const float* __restrict__ targets,
    const float* __restrict__ psc,          // scaled preds
    const unsigned char* __restrict__ pk,   // packed masks
    float* __restrict__ slab)               // [NBLK][4]
{
    const int bid = blockIdx.x;
    const int t   = threadIdx.x;

    // unrank bid -> (g, h), h >= g.  start(g) = 64g - g(g-1)/2
    int g = (int)((129.0 - sqrt(129.0 * 129.0 - 8.0 * (double)bid)) * 0.5);
    while (64 * (g + 1) - ((g + 1) * g) / 2 <= bid) ++g;
    while (64 * g - (g * (g - 1)) / 2 > bid) --g;
    const int h     = g + (bid - (64 * g - (g * (g - 1)) / 2));
    const int i0    = 4 * g;
    const int jbase = 4 * h;

    const float4* psc4 = (const float4*)psc;
    const float4* tgt4 = (const float4*)targets;

    // i-tile in registers: lane t owns l = t and l = t+256 (coalesced 16B)
    float4 pi0[TI], pi1[TI], ti0[TI], ti1[TI];
    unsigned mi[TI];
    #pragma unroll
    for (int r = 0; r < TI; ++r) {
        pi0[r] = psc4[(i0 + r) * 512 + t];
        pi1[r] = psc4[(i0 + r) * 512 + t + 256];
        ti0[r] = tgt4[(i0 + r) * 512 + t];
        ti1[r] = tgt4[(i0 + r) * 512 + t + 256];
        mi[r]  = pk[(i0 + r) * 256 + t];
    }

    float loss[4] = {0.f, 0.f, 0.f, 0.f};

#define ELEM(nn, bit, PIv, PJv, TIv, TJv)                                      \
    {                                                                          \
        const float u  = (PIv) - (PJv);                                        \
        const float td = (TIv) - (TJv);                                        \
        const float up = (td > MARGIN) ? -u : u;                               \
        const float sp = __builtin_log2f(1.0f + __builtin_exp2f(up));          \
        loss[nn] = __builtin_fmaf((float)((mp >> (bit)) & 1u), sp, loss[nn]);  \
    }

    #pragma unroll
    for (int cc = 0; cc < TJ; ++cc) {
        const int j = jbase + cc;                     // block-uniform, <= 255
        const float4  pj0 = psc4[j * 512 + t];
        const float4  pj1 = psc4[j * 512 + t + 256];
        const float4  tj0 = tgt4[j * 512 + t];
        const float4  tj1 = tgt4[j * 512 + t + 256];
        const unsigned mjv = pk[j * 256 + t];

        #pragma unroll
        for (int r = 0; r < TI; ++r) {
            const unsigned ok = ((i0 + r) < j) ? 0xFFu : 0u;   // uniform
            const unsigned mp = mi[r] & mjv & ok;

            ELEM(0, 0, pi0[r].x, pj0.x, ti0[r].x, tj0.x);
            ELEM(1, 1, pi0[r].y, pj0.y, ti0[r].y, tj0.y);
            ELEM(2, 2, pi0[r].z, pj0.z, ti0[r].z, tj0.z);
            ELEM(3, 3, pi0[r].w, pj0.w, ti0[r].w, tj0.w);
            ELEM(0, 4, pi1[r].x, pj1.x, ti1[r].x, tj1.x);
            ELEM(1, 5, pi1[r].y, pj1.y, ti1[r].y, tj1.y);
            ELEM(2, 6, pi1[r].z, pj1.z, ti1[r].z, tj1.z);
            ELEM(3, 7, pi1[r].w, pj1.w, ti1[r].w, tj1.w);
        }
    }
#undef ELEM

    // ---- block reduction: wave shuffle (64 lanes) -> LDS across 4 waves ----
    #pragma unroll
    for (int kk = 0; kk < 4; kk++) {
        #pragma unroll
        for (int off = 32; off > 0; off >>= 1)
            loss[kk] += __shfl_down(loss[kk], off, 64);
    }

    __shared__ float sred[4][4];
    if ((t & 63) == 0) {
        #pragma unroll
        for (int kk = 0; kk < 4; kk++) sred[t >> 6][kk] = loss[kk];
    }
    __syncthreads();

    if (t < 4)
        slab[bid * 4 + t] = sred[0][t] + sred[1][t] + sred[2][t] + sred[3][t];
}

// ---------------------------------------------------------------------------
// Finalize: total = (1/4) * sum_n where(cnt>0, ln2 * loss2_n / (cnt_n+EPS), 0)
// ---------------------------------------------------------------------------
__global__ __launch_bounds__(256) void finalize_kernel(
    const float* __restrict__ slab,
    const float* __restrict__ cntp,
    float* __restrict__ out)
{
    const int t = threadIdx.x;
    const int n = t & 3, g = t >> 2;          // 64 groups x 4 features
    double s = 0.0;
    for (int q = g; q < NBLK; q += 64) s += (double)slab[q * 4 + n];

    __shared__ double sd[260];
    sd[t] = s;
    __syncthreads();

    if (t < 4) {
        double ls = 0.0;
        for (int g2 = 0; g2 < 64; ++g2) ls += sd[g2 * 4 + t];
        double cs = 0.0;
        for (int p = 0; p < 8; ++p) cs += (double)cntp[p * 4 + t];
        sd[256 + t] = (cs > 0.0) ? (LN2 * ls / (cs + 1e-8)) : 0.0;
    }
    __syncthreads();

    if (t == 0)
        out[0] = (float)((sd[256] + sd[257] + sd[258] + sd[259]) * 0.25);
}

extern "C" void kernel_launch(void* const* d_in, const int* in_sizes, int n_in,
                              void* d_out, int out_size, void* d_ws, size_t ws_size,
                              hipStream_t stream)
{
    const float* preds   = (const float*)d_in[0];
    const float* targets = (const float*)d_in[1];
    const int*   masks   = (const int*)d_in[2];   // jnp.bool_ arrives as int32
    float* out = (float*)d_out;

    char* ws = (char*)d_ws;
    float*         slab = (float*)(ws + OFF_SLAB);
    float*         cntp = (float*)(ws + OFF_CNT);
    float*         psc  = (float*)(ws + OFF_PSC);
    unsigned char* pk   = (unsigned char*)(ws + OFF_PK);

    prep_kernel<<<776, 256, 0, stream>>>(preds, masks, psc, pk, cntp);
    pair_bce_kernel<<<NBLK, 256, 0, stream>>>(targets, psc, pk, slab);
    finalize_kernel<<<1, 256, 0, stream>>>(slab, cntp, out);
}

// Round 9
// 62.454 us; speedup vs baseline: 2.3456x; 2.3456x over previous
//
#include <hip/hip_runtime.h>

// Problem constants (reference: B=256, L=512, N=4)
constexpr int B = 256;
constexpr int NPAIRS = (B * (B - 1)) / 2;   // 32640
constexpr int CHUNK  = 16;                  // pairs per block
constexpr int NBLK   = NPAIRS / CHUNK;      // 2040 blocks (exact, all equal work)

#define MARGIN  1e-3f
#define LOG2E   1.4426950408889634f
#define LN2     0.6931471805599453

// ---- workspace layout (bytes) ----
// [0,1024)  double slab[32][4]  loss partials (log2 units);  [1024,1056) double cnt4[4]
// [4096, +2MB) float psc = preds*log2e;  then uchar pk[256][256] packed masks
constexpr size_t OFF_SLAB = 0;
constexpr size_t OFF_CNT  = 1024;
constexpr size_t OFF_PSC  = 4096;
constexpr size_t OFF_PK   = 4096 + 2097152;

__device__ __forceinline__ int pair_start(int i) {  // # pairs before row i
    return (i * (511 - i)) / 2;
}

// ---------------------------------------------------------------------------
// Prep: b<512: psc = preds*log2e; b<768: pack masks (1 byte per (row,lane));
// b<776: cnt4[n] = sum_l C(colcount(l,n),2) exactly (masked-pair count).
// ---------------------------------------------------------------------------
__global__ __launch_bounds__(256) void prep_kernel(
    const float* __restrict__ preds,
    const int*   __restrict__ masks,
    float*        __restrict__ psc,
    unsigned char* __restrict__ pk,
    double*       __restrict__ cnt4)
{
    const int b = blockIdx.x;
    const int t = threadIdx.x;
    __shared__ float sredc[256];

    if (b < 512) {
        const int idx = b * 256 + t;
        float4 v = ((const float4*)preds)[idx];
        v.x *= LOG2E; v.y *= LOG2E; v.z *= LOG2E; v.w *= LOG2E;
        ((float4*)psc)[idx] = v;
    } else if (b < 768) {
        const int r = b - 512;
        const int4 m0 = ((const int4*)masks)[r * 512 + t];        // l = t
        const int4 m1 = ((const int4*)masks)[r * 512 + t + 256];  // l = t+256
        const unsigned byte =
            (unsigned)m0.x | ((unsigned)m0.y << 1) | ((unsigned)m0.z << 2) |
            ((unsigned)m0.w << 3) | ((unsigned)m1.x << 4) | ((unsigned)m1.y << 5) |
            ((unsigned)m1.z << 6) | ((unsigned)m1.w << 7);
        pk[r * 256 + t] = (unsigned char)byte;
    } else {
        const int col = (b - 768) * 256 + t;       // (l, n) column of 2048
        int c = 0;
        #pragma unroll 8
        for (int r = 0; r < 256; ++r) c += masks[r * 2048 + col];
        sredc[t] = (float)((c * (c - 1)) / 2);     // C(c,2), exact in f32
        __syncthreads();
        if (t < 4) {                               // n = col & 3 = t
            float s = 0.f;
            for (int q = t; q < 256; q += 4) s += sredc[q];
            atomicAdd(&cnt4[t], (double)s);
        }
    }
}

// ---------------------------------------------------------------------------
// Main (v3 structure, 55.4us proven: flat 16-pair chunks, i-row register
// cache, sequential j walk). New ELEM: softplus product-folding.
//   sum bce = ln2 * [ sum log2(1+2^u) - sum_{act && tg} u ],  u=(pi-pj)*log2e
// Masked-out elems: up=-inf -> 2^up=0 -> factor 1 (free). One v_log per 4
// elems (fold every 2 iters) instead of per elem: trans cyc/elem 64 -> 40.
// ---------------------------------------------------------------------------
__global__ __launch_bounds__(256) void pair_bce_kernel(
    const float* __restrict__ targets,
    const float* __restrict__ psc,          // scaled preds
    const unsigned char* __restrict__ pk,   // packed masks
    double* __restrict__ slab)              // [32][4]
{
    const int t = threadIdx.x;
    const int k0 = blockIdx.x * CHUNK;

    // unrank k0 -> (i, j)
    int i;
    {
        double d = (511.0 - sqrt(511.0 * 511.0 - 8.0 * (double)k0)) * 0.5;
        i = (int)d;
        while (pair_start(i + 1) <= k0) ++i;
        while (pair_start(i) > k0) --i;
    }
    int j = i + 1 + (k0 - pair_start(i));

    const float4* psc4 = (const float4*)psc;
    const float4* tgt4 = (const float4*)targets;

    float4 pi0, pi1, ti0, ti1;
    unsigned mi;
#define LOAD_I()                                                               \
    {                                                                          \
        pi0 = psc4[i * 512 + t];       pi1 = psc4[i * 512 + t + 256];          \
        ti0 = tgt4[i * 512 + t];       ti1 = tgt4[i * 512 + t + 256];          \
        mi  = pk[i * 256 + t];                                                 \
    }
    LOAD_I();

    float lg[4] = {0.f, 0.f, 0.f, 0.f};     // sum log2(1+2^u) partials
    float s2[4] = {0.f, 0.f, 0.f, 0.f};     // sum_{act&&tg} u
    float pp[4] = {1.f, 1.f, 1.f, 1.f};     // running product of (1+2^u)
    const float NINF = -__builtin_inff();

#define ELEM(nn, bit, PIv, PJv, TIv, TJv)                                      \
    {                                                                          \
        const float u   = (PIv) - (PJv);                                       \
        const bool  act = (mp & (1u << (bit))) != 0u;                          \
        const float up  = act ? u : NINF;                                      \
        const float f   = __builtin_exp2f(up) + 1.0f;                          \
        pp[nn] *= f;                                                           \
        const bool  pos = act && (((TIv) - (TJv)) > MARGIN);                   \
        s2[nn] += pos ? u : 0.0f;                                              \
    }

    #pragma unroll 4
    for (int c = 0; c < CHUNK; ++c) {
        const float4 pj0 = psc4[j * 512 + t];
        const float4 pj1 = psc4[j * 512 + t + 256];
        const float4 tj0 = tgt4[j * 512 + t];
        const float4 tj1 = tgt4[j * 512 + t + 256];
        const unsigned mj = pk[j * 256 + t];
        const unsigned mp = mi & mj;

        ELEM(0, 0, pi0.x, pj0.x, ti0.x, tj0.x);
        ELEM(1, 1, pi0.y, pj0.y, ti0.y, tj0.y);
        ELEM(2, 2, pi0.z, pj0.z, ti0.z, tj0.z);
        ELEM(3, 3, pi0.w, pj0.w, ti0.w, tj0.w);
        ELEM(0, 4, pi1.x, pj1.x, ti1.x, tj1.x);
        ELEM(1, 5, pi1.y, pj1.y, ti1.y, tj1.y);
        ELEM(2, 6, pi1.z, pj1.z, ti1.z, tj1.z);
        ELEM(3, 7, pi1.w, pj1.w, ti1.w, tj1.w);

        // fold every 2 iterations: 4 factors <= 2^64, no f32 overflow
        if (c & 1) {
            #pragma unroll
            for (int k = 0; k < 4; ++k) {
                lg[k] += __builtin_log2f(pp[k]);
                pp[k] = 1.0f;
            }
        }

        if (++j == B) {                 // row exhausted -> next row (uniform)
            ++i;
            if (i >= B - 1) break;      // only possible at c==15
            j = i + 1;
            LOAD_I();
        }
    }
#undef ELEM
#undef LOAD_I

    // final fold (no-op if last fold already ran: log2(1)=0)
    #pragma unroll
    for (int k = 0; k < 4; ++k) lg[k] += __builtin_log2f(pp[k]);

    // per-thread result in log2 units: d[n] = lg[n] - s2[n]
    float d[4];
    #pragma unroll
    for (int k = 0; k < 4; ++k) d[k] = lg[k] - s2[k];

    // ---- block reduction: wave shuffle (64 lanes) -> LDS across 4 waves ----
    #pragma unroll
    for (int kk = 0; kk < 4; kk++) {
        #pragma unroll
        for (int off = 32; off > 0; off >>= 1)
            d[kk] += __shfl_down(d[kk], off, 64);
    }

    __shared__ float sred[4][4];
    if ((t & 63) == 0) {
        #pragma unroll
        for (int kk = 0; kk < 4; kk++) sred[t >> 6][kk] = d[kk];
    }
    __syncthreads();

    if (t < 4) {
        const float v = sred[0][t] + sred[1][t] + sred[2][t] + sred[3][t];
        atomicAdd(&slab[(blockIdx.x & 31) * 4 + t], (double)v);
    }
}

// ---------------------------------------------------------------------------
// Finalize: total = (1/4) * sum_n where(cnt>0, ln2 * loss2_n / (cnt_n+EPS), 0)
// ---------------------------------------------------------------------------
__global__ void finalize_kernel(const double* __restrict__ slab,
                                const double* __restrict__ cnt4,
                                float* __restrict__ out)
{
    double total = 0.0;
    #pragma unroll
    for (int n = 0; n < 4; n++) {
        double ls = 0.0;
        for (int s = 0; s < 32; ++s) ls += slab[s * 4 + n];
        const double cs = cnt4[n];
        total += (cs > 0.0) ? (LN2 * ls / (cs + 1e-8)) : 0.0;
    }
    out[0] = (float)(total / 4.0);
}

extern "C" void kernel_launch(void* const* d_in, const int* in_sizes, int n_in,
                              void* d_out, int out_size, void* d_ws, size_t ws_size,
                              hipStream_t stream)
{
    const float* preds   = (const float*)d_in[0];
    const float* targets = (const float*)d_in[1];
    const int*   masks   = (const int*)d_in[2];   // jnp.bool_ arrives as int32
    float* out = (float*)d_out;

    char* ws = (char*)d_ws;
    double*        slab = (double*)(ws + OFF_SLAB);
    double*        cnt4 = (double*)(ws + OFF_CNT);
    float*         psc  = (float*)(ws + OFF_PSC);
    unsigned char* pk   = (unsigned char*)(ws + OFF_PK);

    // zero accumulators every call (ws is poisoned once, never re-poisoned)
    (void)hipMemsetAsync(ws, 0, 2048, stream);

    prep_kernel<<<776, 256, 0, stream>>>(preds, masks, psc, pk, cnt4);
    pair_bce_kernel<<<NBLK, 256, 0, stream>>>(targets, psc, pk, slab);
    finalize_kernel<<<1, 1, 0, stream>>>(slab, cnt4, out);
}

// Round 10
// 39.147 us; speedup vs baseline: 3.7420x; 1.5953x over previous
//
#include <hip/hip_runtime.h>

// Problem constants (reference: B=256, L=512, N=4)
constexpr int B    = 256;
constexpr int NCOL = 2048;            // (l, n) columns: col = l*4 + n

#define MARGIN 1e-3f
#define LOG2E  1.4426950408889634f
#define LN2    0.6931471805599453

// ---- workspace layout (bytes); every location read is written every call ----
constexpr size_t OFF_SLAB   = 0;      // float slab[2048]    per-column loss (log2 units)
constexpr size_t OFF_CPAIRS = 8192;   // float cpairs[2048]  per-column C(c,2)

// ---------------------------------------------------------------------------
// Fused kernel: one block per (l,n) column.
// 1) Compaction: thread r reads mask/pred/target at (row=r, col); wave ballot
//    + popcount prefix gives each active row its rank; active (u=p*log2e, t)
//    pairs land contiguously in LDS (row order preserved -> rank order == row
//    order, so compacted index a<b  <=>  row i<j).
// 2) Pair loop over ACTIVE rows only (~25% of all pairs -> 4x fewer exps):
//    thread = anchor a, loops b=a+d. bce/ln2 = log2(1+2^(tg ? -x : x)),
//    x = u_a - u_b, tg = (t_a - t_b > margin). Product-fold: one v_log per
//    8 elements (factors <= 2^15, 8 folds < 2^120: no f32 overflow).
// 3) Block-reduce -> slab[col]; C(c,2) -> cpairs[col]. No atomics, no memset.
// ---------------------------------------------------------------------------
__global__ __launch_bounds__(256) void col_pair_kernel(
    const float* __restrict__ preds,
    const float* __restrict__ targets,
    const int*   __restrict__ masks,
    float* __restrict__ slab,
    float* __restrict__ cpairs)
{
    const int col  = blockIdx.x;
    const int t    = threadIdx.x;
    const int lane = t & 63;
    const int wave = t >> 6;

    // --- compaction into LDS (strided gathers; arrays are L2-resident) ---
    const int   mv = masks[t * NCOL + col];
    const float uv = preds[t * NCOL + col] * LOG2E;
    const float tv = targets[t * NCOL + col];

    __shared__ float2 sc[256];
    __shared__ int    wcnt[4];
    __shared__ float  s4[4];

    const unsigned long long bal = __ballot(mv != 0);
    if (lane == 0) wcnt[wave] = __popcll(bal);
    __syncthreads();

    int basr = 0;
    #pragma unroll
    for (int w = 0; w < 4; ++w) basr += (w < wave) ? wcnt[w] : 0;
    const int c = wcnt[0] + wcnt[1] + wcnt[2] + wcnt[3];

    if (mv) {
        const int rank = basr + __popcll(bal & ((1ull << lane) - 1ull));
        sc[rank] = make_float2(uv, tv);
    }
    __syncthreads();

    // --- pair loop over compacted actives ---
    float lg = 0.f, pp = 1.f;
    if (t < c) {
        const float2 av = sc[t];
        for (int d = 1; d < c - t; ++d) {           // d uniform across lanes
            const float2 bv = sc[t + d];
            const float x  = av.x - bv.x;
            const float td = av.y - bv.y;
            const float xp = (td > MARGIN) ? -x : x;
            pp *= (__builtin_exp2f(xp) + 1.0f);
            if ((d & 7) == 0) { lg += __builtin_log2f(pp); pp = 1.f; }
        }
    }
    lg += __builtin_log2f(pp);                      // log2(1)=0 for idle lanes

    // --- block reduction: wave shuffle -> LDS across 4 waves ---
    #pragma unroll
    for (int off = 32; off > 0; off >>= 1)
        lg += __shfl_down(lg, off, 64);
    if (lane == 0) s4[wave] = lg;
    __syncthreads();

    if (t == 0) {
        slab[col]   = s4[0] + s4[1] + s4[2] + s4[3];
        cpairs[col] = (float)((c * (c - 1)) / 2);   // exact in f32 (<= 32640)
    }
}

// ---------------------------------------------------------------------------
// Finalize: loss_n = sum_{col%4==n} slab[col];  cnt_n = sum cpairs[col];
// total = (1/4) * sum_n where(cnt>0, ln2 * loss_n / (cnt_n + EPS), 0)
// ---------------------------------------------------------------------------
__global__ __launch_bounds__(256) void finalize_kernel(
    const float* __restrict__ slab,
    const float* __restrict__ cpairs,
    float* __restrict__ out)
{
    const int t = threadIdx.x;
    double ls = 0.0, cs = 0.0;
    for (int q = t; q < NCOL; q += 256) {           // q%4 == t%4 (stride 256)
        ls += (double)slab[q];
        cs += (double)cpairs[q];
    }

    __shared__ double sl[256], sp[256], res[4];
    sl[t] = ls; sp[t] = cs;
    __syncthreads();

    if (t < 4) {
        double lsn = 0.0, csn = 0.0;
        for (int g = t; g < 256; g += 4) { lsn += sl[g]; csn += sp[g]; }
        res[t] = (csn > 0.0) ? (LN2 * lsn / (csn + 1e-8)) : 0.0;
    }
    __syncthreads();

    if (t == 0)
        out[0] = (float)((res[0] + res[1] + res[2] + res[3]) * 0.25);
}

extern "C" void kernel_launch(void* const* d_in, const int* in_sizes, int n_in,
                              void* d_out, int out_size, void* d_ws, size_t ws_size,
                              hipStream_t stream)
{
    const float* preds   = (const float*)d_in[0];
    const float* targets = (const float*)d_in[1];
    const int*   masks   = (const int*)d_in[2];   // jnp.bool_ arrives as int32
    float* out = (float*)d_out;

    char* ws = (char*)d_ws;
    float* slab   = (float*)(ws + OFF_SLAB);
    float* cpairs = (float*)(ws + OFF_CPAIRS);

    col_pair_kernel<<<NCOL, 256, 0, stream>>>(preds, targets, masks, slab, cpairs);
    finalize_kernel<<<1, 256, 0, stream>>>(slab, cpairs, out);
}